// Round 1
// 625.914 us; speedup vs baseline: 1.0357x; 1.0357x over previous
//
#include <hip/hip_runtime.h>
#include <math.h>

#define DEV_INLINE __device__ __forceinline__

constexpr int Nn = 256;
constexpr size_t SZW = (size_t)16 * 256 * 256 * 16;  // 16,777,216
constexpr size_t SZB = (size_t)16 * 256 * 16;        // 65,536
constexpr size_t OSTRIDE = SZW + SZB;                // per-layer output stride

// workspace layout (float offsets)
constexpr int T_GT  = 0;          // global_terms [4][4][4][256]   = 16384
constexpr int T_DT  = 16384;      // diag_terms   [6][4][256]      = 6144
constexpr int T_P1  = 22528;      // diag_p1      [2][3][256]      = 1536
constexpr int T_M1  = 24064;      // diag_m1      [2][3][256]      = 1536
constexpr int O_RSF = 25600;      // rsum final [64][256][16]      = 262144
constexpr int O_CS  = 287744;     // csum       [64][256][16]      = 262144
constexpr int O_AS  = 549888;     // allsum raw [64][16]           = 1024
constexpr int O_BS  = 550912;     // bsum raw   [64][16]           = 1024
constexpr int O_AROW= 551936;     // Arow [64][256][16]            = 262144
constexpr int O_BCOL= 814080;     // Bcol [64][256][16]            = 262144
constexpr int O_RSP = 1076224;    // rsum partials [64][32][256][16] = 8,388,608 (32 MB)

DEV_INLINE void f4acc(float4& a, const float4 b) { a.x += b.x; a.y += b.y; a.z += b.z; a.w += b.w; }
DEV_INLINE float4 f4add(const float4 a, const float4 b) { return make_float4(a.x + b.x, a.y + b.y, a.z + b.z, a.w + b.w); }
DEV_INLINE void f4fma(float4& a, float s, const float4 t) {
    a.x = fmaf(s, t.x, a.x); a.y = fmaf(s, t.y, a.y);
    a.z = fmaf(s, t.z, a.z); a.w = fmaf(s, t.w, a.w);
}
DEV_INLINE void f4shfl_xor_acc(float4& a, int m) {
    a.x += __shfl_xor(a.x, m); a.y += __shfl_xor(a.y, m);
    a.z += __shfl_xor(a.z, m); a.w += __shfl_xor(a.w, m);
}

// ---------------- SIREN: 100 points through 3->64->64->64->256 ----------------
__global__ __launch_bounds__(64) void siren_kernel(
    const float* __restrict__ sw0, const float* __restrict__ sb0,
    const float* __restrict__ sw1, const float* __restrict__ sb1,
    const float* __restrict__ sw2, const float* __restrict__ sb2,
    const float* __restrict__ swo, const float* __restrict__ sbo,
    float* __restrict__ ws) {
    __shared__ float h[64];
    const int p = blockIdx.x, t = threadIdx.x;
    const float lv[4] = {-1.f, -1.f / 3.f, 1.f / 3.f, 1.f};
    float x, y, tt;
    if (p < 64)      { int tm = p >> 4, a = (p >> 2) & 3, bb = p & 3; x = lv[a];   y = lv[bb];  tt = -1.f + 2.f * tm / 13.f; }
    else if (p < 88) { int q = p - 64; int tm = q >> 2, a = q & 3;    x = lv[a];   y = lv[a];   tt = -1.f + 2.f * (4 + tm) / 13.f; }
    else if (p < 94) { int q = p - 88; int tm = q / 3, a = q % 3;     x = lv[a];   y = lv[a+1]; tt = -1.f + 2.f * (10 + tm) / 13.f; }
    else             { int q = p - 94; int tm = q / 3, a = q % 3;     x = lv[a+1]; y = lv[a];   tt = -1.f + 2.f * (12 + tm) / 13.f; }
    float v = sinf(30.f * (x * sw0[t] + y * sw0[64 + t] + tt * sw0[128 + t] + sb0[t]));
    h[t] = v; __syncthreads();
    float v1 = sb1[t];
    for (int u = 0; u < 64; ++u) v1 += h[u] * sw1[u * 64 + t];
    v1 = sinf(v1);
    __syncthreads(); h[t] = v1; __syncthreads();
    float v2 = sb2[t];
    for (int u = 0; u < 64; ++u) v2 += h[u] * sw2[u * 64 + t];
    v2 = sinf(v2);
    __syncthreads(); h[t] = v2; __syncthreads();
    const float inv_fn = 0.06454972243679028f;  // 1/sqrt(240)
    for (int m = 0; m < 4; ++m) {
        int o = m * 64 + t;
        float vo = sbo[o];
        for (int u = 0; u < 64; ++u) vo += h[u] * swo[u * 256 + o];
        ws[p * 256 + o] = vo * inv_fn;
    }
}

// ---------------- bias sums: bsum[l][b][c] = sum_n bias_l[b,n,c] ----------------
__global__ __launch_bounds__(64) void reduce_b_kernel(
    const float4* __restrict__ b0, const float4* __restrict__ b1,
    const float4* __restrict__ b2, const float4* __restrict__ b3,
    float* __restrict__ ws) {
    const int z = blockIdx.x;  // l*16+b
    const int l = z >> 4, b = z & 15;
    const float4* bp = ((l == 0) ? b0 : (l == 1) ? b1 : (l == 2) ? b2 : b3) + (size_t)b * Nn * 4;
    const int lane = threadIdx.x;
    const int c4 = lane & 3, part = lane >> 2;
    float4 acc = make_float4(0.f, 0.f, 0.f, 0.f);
    for (int s = 0; s < 16; ++s) f4acc(acc, bp[(size_t)(part + s * 16) * 4 + c4]);
#pragma unroll
    for (int m = 4; m < 64; m <<= 1) f4shfl_xor_acc(acc, m);
    if (lane < 4) {
        float* dst = ws + O_BS + (size_t)z * 16 + lane * 4;
        dst[0] = acc.x; dst[1] = acc.y; dst[2] = acc.z; dst[3] = acc.w;
    }
}

// -------- streaming weight reduction: atomic-free csum + rsum strip partials --------
// block = (strip of 8 j-rows, l*8+bg). Streams 8 rows x 16 KB straight from HBM:
//   csum[j][c]   : full (all 256 k in-block) -> wave shfl_xor + tiny LDS combine, direct store
//   rsum partial : per-thread register acc over the strip -> contiguous 16 KB store
//   allsum       : block partial -> 16 atomics/block (8K atomics total vs 4M before)
__global__ __launch_bounds__(256) void reduce_w_kernel(
    const float4* __restrict__ w0, const float4* __restrict__ w1,
    const float4* __restrict__ w2, const float4* __restrict__ w3,
    float* __restrict__ ws, int bbase) {
    const int strip = blockIdx.x;            // 0..31  (8 rows each)
    const int lbg = blockIdx.y;              // 0..31  (l*8 + bg)
    const int l = lbg >> 3, b = bbase + (lbg & 7);
    const float4* __restrict__ w = (l == 0) ? w0 : (l == 1) ? w1 : (l == 2) ? w2 : w3;
    const int tid = threadIdx.x;
    const int wv = tid >> 6, lane = tid & 63;
    const int plb = l * 16 + b;

    __shared__ float4 csbuf[8][4][4];        // [row][wave][c4]
    __shared__ float4 abuf[4][4];            // [wave][c4]

    float4 racc0 = make_float4(0, 0, 0, 0), racc1 = racc0, racc2 = racc0, racc3 = racc0;
    const size_t rowb = ((size_t)(b * Nn + strip * 8)) * 1024;  // float4 units

#pragma unroll
    for (int r = 0; r < 8; ++r) {
        const float4* wp = w + rowb + (size_t)r * 1024 + tid;
        float4 v0 = wp[0], v1 = wp[256], v2 = wp[512], v3 = wp[768];
        f4acc(racc0, v0); f4acc(racc1, v1); f4acc(racc2, v2); f4acc(racc3, v3);
        float4 s = f4add(f4add(v0, v1), f4add(v2, v3));  // partial over this thread's 4 k
        // reduce over the wave's 16 kq slots (lane bits 2..5), c4 preserved
        f4shfl_xor_acc(s, 4); f4shfl_xor_acc(s, 8);
        f4shfl_xor_acc(s, 16); f4shfl_xor_acc(s, 32);
        if (lane < 4) csbuf[r][wv][lane] = s;            // lane == c4 here
    }
    __syncthreads();

    // csum final: 32 threads, one float4 each, contiguous 512 B store
    if (tid < 32) {
        const int r = tid >> 2, cc = tid & 3;
        float4 cv = f4add(f4add(csbuf[r][0][cc], csbuf[r][1][cc]),
                          f4add(csbuf[r][2][cc], csbuf[r][3][cc]));
        ((float4*)(ws + O_CS))[(size_t)(plb * Nn + strip * 8 + r) * 4 + cc] = cv;
    }

    // rsum strip partial: thread owns (k = kq+64i, c4); layout matches [k][c], coalesced
    float4* part = (float4*)(ws + O_RSP) + (size_t)(plb * 32 + strip) * 1024;
    part[tid]       = racc0;
    part[256 + tid] = racc1;
    part[512 + tid] = racc2;
    part[768 + tid] = racc3;

    // allsum block partial
    float4 a = f4add(f4add(racc0, racc1), f4add(racc2, racc3));
    f4shfl_xor_acc(a, 4); f4shfl_xor_acc(a, 8);
    f4shfl_xor_acc(a, 16); f4shfl_xor_acc(a, 32);
    if (lane < 4) abuf[wv][lane] = a;
    __syncthreads();
    if (tid < 4) {
        float4 av = f4add(f4add(abuf[0][tid], abuf[1][tid]), f4add(abuf[2][tid], abuf[3][tid]));
        float* dst = ws + O_AS + (size_t)plb * 16 + tid * 4;
        atomicAdd(dst + 0, av.x); atomicAdd(dst + 1, av.y);
        atomicAdd(dst + 2, av.z); atomicAdd(dst + 3, av.w);
    }
}

// -------- fold the 32 rsum strip partials -> final rsum (same layout as before) --------
__global__ __launch_bounds__(256) void fold_rs_kernel(float* __restrict__ ws, int bbase) {
    const int g = blockIdx.x * 256 + threadIdx.x;   // 0..32767 per group
    const int rest = g & 1023, lbg = g >> 10;       // rest = k*4 + c4 (float4 units)
    const int l = lbg >> 3, b = bbase + (lbg & 7);
    const int plb = l * 16 + b;
    const float4* part = (const float4*)(ws + O_RSP) + (size_t)(plb * 32) * 1024 + rest;
    float4 acc = part[0];
#pragma unroll
    for (int s = 1; s < 32; ++s) f4acc(acc, part[(size_t)s * 1024]);
    ((float4*)(ws + O_RSF))[(size_t)plb * 1024 + rest] = acc;
}

// ------- assemble Arow/Bcol broadcast vectors + the ob outputs -------
__global__ __launch_bounds__(256) void vectors_kernel(
    const float* __restrict__ bias0, const float* __restrict__ bias1,
    const float* __restrict__ bias2, const float* __restrict__ bias3,
    float* __restrict__ ws, float* __restrict__ out, int bbase) {
    const int g = blockIdx.x * 256 + threadIdx.x;  // covers l(4) x bg(8) x n(256) x d(16)
    const int d = g & 15, n = (g >> 4) & 255, bg = (g >> 12) & 7, l = g >> 15;
    const int b = bbase + bg;
    const float invN = 1.f / 256.f, invNN = 1.f / 65536.f;
    const float* bias[4] = {bias0, bias1, bias2, bias3};
    const size_t rowi = (size_t)((l * 16 + b) * 256 + n) * 16;
    const float* cs = ws + O_CS + rowi;
    const float* rs = ws + O_RSF + rowi;
    const float* bv = bias[l] + (size_t)(b * 256 + n) * 16;
    const float* dt = ws + T_DT;
    const float* Twrow  = dt + (0 * 4 + l) * 256;
    const float* Twcol  = dt + (1 * 4 + l) * 256;
    const float* Twb    = dt + (3 * 4 + l) * 256;
    const float* Tbwcol = dt + (4 * 4 + l) * 256;
    const float* Tbb    = dt + (5 * 4 + l) * 256;
    float arow = 0.f, bcol = 0.f, ob = 0.f;
#pragma unroll
    for (int c = 0; c < 16; ++c) {
        float cm = cs[c] * invN, rm = rs[c] * invN, bb = bv[c];
        arow += cm * Twcol[c * 16 + d];
        bcol += rm * Twrow[c * 16 + d] + bb * Twb[c * 16 + d];
        ob   += rm * Tbwcol[c * 16 + d] + bb * Tbb[c * 16 + d];
    }
    if (l > 0) {
        const float* rsm = ws + O_RSF + (size_t)(((l - 1) * 16 + b) * 256 + n) * 16;
        const float* bvm = bias[l - 1] + (size_t)(b * 256 + n) * 16;
        const float* Twm1 = ws + T_M1 + (l - 1) * 256;
        const float* Tbm1 = ws + T_M1 + (3 + l - 1) * 256;
#pragma unroll
        for (int c = 0; c < 16; ++c)
            arow += rsm[c] * invN * Twm1[c * 16 + d] + bvm[c] * Tbm1[c * 16 + d];
    }
    if (l < 3) {
        const float* csp = ws + O_CS + (size_t)(((l + 1) * 16 + b) * 256 + n) * 16;
        const float* Twp1  = ws + T_P1 + l * 256;
        const float* Tbwp1 = ws + T_P1 + (3 + l) * 256;
#pragma unroll
        for (int c = 0; c < 16; ++c) {
            float cp = csp[c] * invN;
            bcol += cp * Twp1[c * 16 + d];
            ob   += cp * Tbwp1[c * 16 + d];
        }
    }
#pragma unroll
    for (int ll = 0; ll < 4; ++ll) {  // batch-global const terms
        const float* as_ = ws + O_AS + (size_t)(ll * 16 + b) * 16;
        const float* bs_ = ws + O_BS + (size_t)(ll * 16 + b) * 16;
        const float* g0 = ws + ((0 * 4 + l) * 4 + ll) * 256;
        const float* g1 = ws + ((1 * 4 + l) * 4 + ll) * 256;
        const float* g2 = ws + ((2 * 4 + l) * 4 + ll) * 256;
        const float* g3 = ws + ((3 * 4 + l) * 4 + ll) * 256;
#pragma unroll
        for (int c = 0; c < 16; ++c) {
            float am = as_[c] * invNN, bm = bs_[c] * invN;
            arow += am * g0[c * 16 + d] + bm * g1[c * 16 + d];
            ob   += am * g2[c * 16 + d] + bm * g3[c * 16 + d];
        }
    }
    ws[O_AROW + rowi + d] = arow;
    ws[O_BCOL + rowi + d] = bcol;
    out[(size_t)l * OSTRIDE + SZW + (size_t)(b * 256 + n) * 16 + d] = ob;
}

// ------- main transform: ow = w . T + Arow + Bcol -------
__global__ __launch_bounds__(256) void transform_kernel(
    const float4* __restrict__ w0, const float4* __restrict__ w1,
    const float4* __restrict__ w2, const float4* __restrict__ w3,
    const float* __restrict__ ws, float4* __restrict__ out, int bbase) {
    const int j = blockIdx.x, bg = blockIdx.y, l = blockIdx.z;
    const int b = bbase + bg;
    const float4* __restrict__ w = (l == 0) ? w0 : (l == 1) ? w1 : (l == 2) ? w2 : w3;
    const int tid = threadIdx.x;
    const int d4 = tid & 3, kk = tid >> 2;
    const float4* T4 = (const float4*)ws + (T_DT / 4) + (2 * 4 + l) * 64;  // t_w_w[l]
    float4 t[16];
#pragma unroll
    for (int c = 0; c < 16; ++c) t[c] = T4[c * 4 + d4];
    const size_t rowbase = (size_t)(b * 256 + j) * 256;
    const float4* Ar = (const float4*)(ws + O_AROW);
    const float4* Bc = (const float4*)(ws + O_BCOL) + (size_t)(l * 16 + b) * 256 * 4 + d4;
    const float4 arow = Ar[(size_t)((l * 16 + b) * 256 + j) * 4 + d4];
    const size_t outb = (size_t)l * (OSTRIDE / 4) + rowbase * 4 + d4;
#pragma unroll
    for (int s = 0; s < 4; ++s) {
        const int k = s * 64 + kk;
        float4 acc = f4add(arow, Bc[(size_t)k * 4]);
        const float4* wp = w + (rowbase + k) * 4;
        float4 v0 = wp[0], v1 = wp[1], v2 = wp[2], v3 = wp[3];
        f4fma(acc, v0.x, t[0]);  f4fma(acc, v0.y, t[1]);  f4fma(acc, v0.z, t[2]);  f4fma(acc, v0.w, t[3]);
        f4fma(acc, v1.x, t[4]);  f4fma(acc, v1.y, t[5]);  f4fma(acc, v1.z, t[6]);  f4fma(acc, v1.w, t[7]);
        f4fma(acc, v2.x, t[8]);  f4fma(acc, v2.y, t[9]);  f4fma(acc, v2.z, t[10]); f4fma(acc, v2.w, t[11]);
        f4fma(acc, v3.x, t[12]); f4fma(acc, v3.y, t[13]); f4fma(acc, v3.z, t[14]); f4fma(acc, v3.w, t[15]);
        out[outb + (size_t)k * 4] = acc;
    }
}

extern "C" void kernel_launch(void* const* d_in, const int* in_sizes, int n_in,
                              void* d_out, int out_size, void* d_ws, size_t ws_size,
                              hipStream_t stream) {
    const float *W[4], *Bv[4], *S[8];
    if (in_sizes[1] == in_sizes[0]) {  // grouped w0..w3,b0..b3
        for (int i = 0; i < 4; ++i) { W[i] = (const float*)d_in[i]; Bv[i] = (const float*)d_in[4 + i]; }
    } else {                           // interleaved
        for (int i = 0; i < 4; ++i) { W[i] = (const float*)d_in[2 * i]; Bv[i] = (const float*)d_in[2 * i + 1]; }
    }
    for (int k = 0; k < 8; ++k) S[k] = (const float*)d_in[8 + k];
    float* ws = (float*)d_ws;
    float* out = (float*)d_out;

    // only the tiny allsum accumulator needs zeroing now (4 KB, was 2.1 MB)
    hipMemsetAsync(ws + O_AS, 0, 1024 * sizeof(float), stream);
    siren_kernel<<<100, 64, 0, stream>>>(S[0], S[1], S[2], S[3], S[4], S[5], S[6], S[7], ws);
    reduce_b_kernel<<<64, 64, 0, stream>>>((const float4*)Bv[0], (const float4*)Bv[1],
                                           (const float4*)Bv[2], (const float4*)Bv[3], ws);
    // 2 batch groups of 8: each group's 128 MB of w stays resident in the 256 MB
    // Infinity Cache between the reduction pass and the transform's re-read.
    for (int g = 0; g < 2; ++g) {
        const int bbase = 8 * g;
        reduce_w_kernel<<<dim3(32, 32), 256, 0, stream>>>(
            (const float4*)W[0], (const float4*)W[1], (const float4*)W[2], (const float4*)W[3], ws, bbase);
        fold_rs_kernel<<<128, 256, 0, stream>>>(ws, bbase);
        vectors_kernel<<<512, 256, 0, stream>>>(Bv[0], Bv[1], Bv[2], Bv[3], ws, out, bbase);
        transform_kernel<<<dim3(256, 8, 4), 256, 0, stream>>>(
            (const float4*)W[0], (const float4*)W[1], (const float4*)W[2], (const float4*)W[3],
            ws, (float4*)out, bbase);
    }
}